// Round 12
// baseline (86.222 us; speedup 1.0000x reference)
//
#include <hip/hip_runtime.h>
#include <math.h>

typedef __attribute__((ext_vector_type(8))) short short8;
typedef __attribute__((ext_vector_type(4))) float f32x4;
typedef __attribute__((ext_vector_type(8))) unsigned short u16x8;

#define TAUF 32.0f
#define SB() __builtin_amdgcn_sched_barrier(0)
#define BAR() __builtin_amdgcn_s_barrier()

// LDS buffer layout (per double-buffer half, BK=64):
//   [A: 64 rows x 64k f32, swizzled slots, 16K][B: ks0 hi 12K|ks0 lo 12K|
//    ks1 hi 12K|ks1 lo 12K = 48K]  -> BUF = 64K; two buffers = 128K.
constexpr int A_SZ  = 16384;
constexpr int BUF   = 65536;
constexpr int CSTR  = 196;     // epilogue C row stride (floats)

// ---------------------------------------------------------------------------
// Kernel 1: PR rows = memory[dm].W as split-bf16 planes [192][768].
// ---------------------------------------------------------------------------
__global__ __launch_bounds__(768) void precompute_pr(
    const float* __restrict__ Wt, const float* __restrict__ Wd,
    const float* __restrict__ mem, unsigned short* __restrict__ PRhi,
    unsigned short* __restrict__ PRlo) {
  int r0 = blockIdx.x * 6, t = threadIdx.x;
  if (r0 >= 180) {
    #pragma unroll
    for (int rr = 0; rr < 6; ++rr) {
      PRhi[(size_t)(r0 + rr) * 768 + t] = 0;
      PRlo[(size_t)(r0 + rr) * 768 + t] = 0;
    }
    return;
  }
  __shared__ float mlds[1536];
  const float* W = (r0 >= 90) ? Wd : Wt;
  int dm0 = (r0 >= 90) ? r0 - 90 : r0;
  for (int i = t; i < 1536; i += 768) mlds[i] = mem[(size_t)dm0 * 256 + i];
  __syncthreads();
  float a[6] = {0.f, 0.f, 0.f, 0.f, 0.f, 0.f};
  #pragma unroll 4
  for (int e = 0; e < 256; ++e) {
    float w = W[(size_t)e * 768 + t];
    #pragma unroll
    for (int rr = 0; rr < 6; ++rr) a[rr] += mlds[rr * 256 + e] * w;
  }
  #pragma unroll
  for (int rr = 0; rr < 6; ++rr) {
    unsigned int bu = __float_as_uint(a[rr]);
    unsigned short hi = (unsigned short)(bu >> 16);
    float hf = __uint_as_float(bu & 0xffff0000u);
    unsigned short lo = (unsigned short)(__float_as_uint(a[rr] - hf) >> 16);
    PRhi[(size_t)(r0 + rr) * 768 + t] = hi;
    PRlo[(size_t)(r0 + rr) * 768 + t] = lo;
  }
}

// ---------------------------------------------------------------------------
// Kernel 2: fused split-bf16 MFMA GEMM [64 x 192 x 768], BK=64 (12 ktiles,
// half the phases of BK=32). 256 threads = 4 waves (2 rg x 2 cg); wave owns
// 32 rows x 96 cols, 72 MFMA/ktile. All operands via LDS (no reg-A ordering
// hazard); counted vmcnt(16); setprio around MFMA; 2 barriers/ktile.
// ---------------------------------------------------------------------------
__global__ __launch_bounds__(256) void fused_mfma(
    const float* __restrict__ feat, const unsigned short* __restrict__ PRhi,
    const unsigned short* __restrict__ PRlo, float* __restrict__ out) {
  __shared__ f32x4 smemv[8192];    // 131072 B; C tile (50176 B) overlays buf0
  __shared__ float invn[64];
  __shared__ float sarr[576];
  char* smem = (char*)smemv;

  const int t    = threadIdx.x;
  const int lane = t & 63;
  const int wid  = t >> 6;         // 0..3
  const int rg   = wid >> 1;       // 0..1: rows rg*32..+31
  const int cg   = wid & 1;        // cols cg*96..+95
  const int b0   = blockIdx.x * 64;
  const char* featB = (const char*)feat;

  // ---- A staging: 16 instrs/ktile (4/wave). Slot grid G=0..1023:
  // row = G>>4, slot s = G&15 holds logical k-granule kq = s ^ (row&15).
  // Source rows are dense (4 x 64B lines per 256B row-tile).
  auto issueA = [&](int kt, int bb) {
    #pragma unroll
    for (int u = 0; u < 4; ++u) {
      int G   = (wid * 4 + u) * 64 + lane;
      int row = G >> 4;
      int s   = G & 15;
      int kq  = s ^ (row & 15);
      const char* src = featB + (size_t)(b0 + row) * 3072 + kt * 256 + kq * 16;
      char* dst = smem + bb * BUF + G * 16;
      __builtin_amdgcn_global_load_lds((const unsigned int*)src,
                                       (unsigned int*)dst, 16, 0, 0);
    }
  };

  // ---- B staging: 48 instrs/ktile (12/wave): [pl][ks][ch] with the R4
  // XOR-granule source swizzle within each 64B k-half line.
  const int bc   = lane >> 2;
  const int bsw  = (lane & 3) ^ ((bc >> 1) & 3);
  const int bsrc = bc * 1536 + bsw * 16;

  auto issueB = [&](int kt, int bb) {
    #pragma unroll
    for (int u = 0; u < 12; ++u) {
      int i  = wid * 12 + u;        // 0..47
      int pl = i >= 24;
      int j  = pl ? i - 24 : i;     // 0..23
      int ks = j >= 12;
      int ch = ks ? j - 12 : j;     // 0..11
      const unsigned short* basep = pl ? PRlo : PRhi;
      const char* gg = (const char*)basep + (size_t)ch * 16 * 1536 +
                       kt * 128 + ks * 64 + bsrc;
      char* l = smem + bb * BUF + A_SZ + ks * 24576 + (pl ? 12288 : 0) +
                ch * 1024 + lane * 16;
      __builtin_amdgcn_global_load_lds((const unsigned int*)gg,
                                       (unsigned int*)l, 16, 0, 0);
    }
  };

  // ---- B fragment read offset (matches source swizzle, conflict-free)
  const int bfr = ((lane & 15) << 6) |
                  ((((lane >> 4) ^ (((lane & 15) >> 1) & 3)) & 3) << 4);

  f32x4 acc0[6], acc1[6];
  #pragma unroll
  for (int j = 0; j < 6; ++j) {
    acc0[j] = (f32x4){0.f, 0.f, 0.f, 0.f};
    acc1[j] = (f32x4){0.f, 0.f, 0.f, 0.f};
  }
  float ssq0 = 0.f, ssq1 = 0.f;

  short8 ah0, al0, ah1, al1;

  // read A frags (k-half ks) from swizzled LDS + cvt to split bf16 + ssq
  auto readA = [&](int bb, int ks) {
    char* base = smem + bb * BUF;
    const int c = lane >> 4;
    #pragma unroll
    for (int rt = 0; rt < 2; ++rt) {
      int row = rg * 32 + rt * 16 + (lane & 15);
      int k0  = ks * 8 + 2 * c;
      int p0  = k0 ^ (row & 15);
      int p1  = (k0 + 1) ^ (row & 15);
      f32x4 v0 = *(const f32x4*)(base + row * 256 + p0 * 16);
      f32x4 v1 = *(const f32x4*)(base + row * 256 + p1 * 16);
      float xs[8] = {v0[0], v0[1], v0[2], v0[3], v1[0], v1[1], v1[2], v1[3]};
      u16x8 h, l;
      float ss = 0.f;
      #pragma unroll
      for (int e = 0; e < 8; ++e) {
        float x = xs[e];
        ss += x * x;
        unsigned int bu = __float_as_uint(x);
        h[e] = (unsigned short)(bu >> 16);
        l[e] = (unsigned short)(__float_as_uint(
                   x - __uint_as_float(bu & 0xffff0000u)) >> 16);
      }
      if (rt == 0) { ah0 = (short8)h; al0 = (short8)l; ssq0 += ss; }
      else         { ah1 = (short8)h; al1 = (short8)l; ssq1 += ss; }
    }
  };

  auto domfma = [&](int bb, int ks) {
    char* base = smem + bb * BUF + A_SZ + ks * 24576;
    __builtin_amdgcn_s_setprio(1);
    #pragma unroll
    for (int j = 0; j < 6; ++j) {
      int chb = (cg * 6 + j) * 1024;
      short8 bh = *(const short8*)(base + chb + bfr);
      short8 bl = *(const short8*)(base + 12288 + chb + bfr);
      acc0[j] = __builtin_amdgcn_mfma_f32_16x16x32_bf16(ah0, bh, acc0[j], 0, 0, 0);
      acc0[j] = __builtin_amdgcn_mfma_f32_16x16x32_bf16(al0, bh, acc0[j], 0, 0, 0);
      acc0[j] = __builtin_amdgcn_mfma_f32_16x16x32_bf16(ah0, bl, acc0[j], 0, 0, 0);
      acc1[j] = __builtin_amdgcn_mfma_f32_16x16x32_bf16(ah1, bh, acc1[j], 0, 0, 0);
      acc1[j] = __builtin_amdgcn_mfma_f32_16x16x32_bf16(al1, bh, acc1[j], 0, 0, 0);
      acc1[j] = __builtin_amdgcn_mfma_f32_16x16x32_bf16(ah1, bl, acc1[j], 0, 0, 0);
    }
    __builtin_amdgcn_s_setprio(0);
  };

#define COMPUTE(bb)                                                          \
  readA(bb, 0);                                                              \
  domfma(bb, 0);                                                             \
  readA(bb, 1);                                                              \
  domfma(bb, 1);

  // ---- prologue: stage tiles 0,1 (16 vmem/wave each); certify tile 0
  issueA(0, 0); issueB(0, 0);
  issueA(1, 1); issueB(1, 1);
  asm volatile("s_waitcnt vmcnt(16)" ::: "memory");
  SB(); BAR();

  // ---- main loop: 2 ktiles/iter; 12 ktiles total
  for (int kp = 0; kp < 5; ++kp) {
    int kt = 2 * kp;
    COMPUTE(0)
    SB(); BAR();
    issueA(kt + 2, 0); issueB(kt + 2, 0);
    asm volatile("s_waitcnt vmcnt(16)" ::: "memory");  // tile kt+1 landed
    SB(); BAR();
    COMPUTE(1)
    SB(); BAR();
    issueA(kt + 3, 1); issueB(kt + 3, 1);
    asm volatile("s_waitcnt vmcnt(16)" ::: "memory");  // tile kt+2 landed
    SB(); BAR();
  }
  // tail: kt=10 (buf0), kt=11 (buf1, already in flight)
  COMPUTE(0)
  SB(); BAR();
  asm volatile("s_waitcnt vmcnt(0)" ::: "memory");     // tile 11 landed
  SB(); BAR();
  COMPUTE(1)
#undef COMPUTE

  // ---- row L2-norm: lanes l, l+16, l+32, l+48 hold the 4 c-chunk partials
  float v0 = ssq0, v1 = ssq1;
  v0 += __shfl_xor(v0, 16, 64); v0 += __shfl_xor(v0, 32, 64);
  v1 += __shfl_xor(v1, 16, 64); v1 += __shfl_xor(v1, 32, 64);
  if (cg == 0 && lane < 16) {
    invn[rg * 32 + lane]      = rsqrtf(v0);
    invn[rg * 32 + 16 + lane] = rsqrtf(v1);
  }
  __syncthreads();   // all LDS reads drained; invn visible; smem reusable

  // ---- write scaled C (q|r) to LDS (single phase: 64 x 196 f32 in buf0)
  float* Clds = (float*)smem;
  #pragma unroll
  for (int rt = 0; rt < 2; ++rt) {
    int rbase = rg * 32 + rt * 16 + ((lane >> 4) << 2);
    #pragma unroll
    for (int j = 0; j < 6; ++j) {
      int col = cg * 96 + j * 16 + (lane & 15);
      f32x4 v = rt ? acc1[j] : acc0[j];
      #pragma unroll
      for (int jj = 0; jj < 4; ++jj)
        Clds[(rbase + jj) * CSTR + col] = v[jj] * invn[rbase + jj];
    }
  }
  __syncthreads();

  // ---- per (row,d): softmax over m, dot with r
  for (int pid = t; pid < 576; pid += 256) {
    int row = pid / 9, d = pid - row * 9;
    const float* qp = Clds + row * CSTR + d * 10;
    const float* rp = qp + 90;
    float mx = qp[0];
    #pragma unroll
    for (int m = 1; m < 10; ++m) mx = fmaxf(mx, qp[m]);
    float s = 0.f, val = 0.f;
    #pragma unroll
    for (int m = 0; m < 10; ++m) {
      float e = __expf(TAUF * (qp[m] - mx));
      s += e;
      val += e * rp[m];
    }
    sarr[pid] = val / s;
  }
  __syncthreads();

  // ---- per row: softmax over d, write out
  if (t < 64) {
    float v2[9];
    #pragma unroll
    for (int d = 0; d < 9; ++d) v2[d] = sarr[t * 9 + d];
    float mx = v2[0];
    #pragma unroll
    for (int d = 1; d < 9; ++d) mx = fmaxf(mx, v2[d]);
    float s = 0.f;
    float e[9];
    #pragma unroll
    for (int d = 0; d < 9; ++d) {
      e[d] = __expf(TAUF * (v2[d] - mx));
      s += e[d];
    }
    float is = 1.f / s;
    #pragma unroll
    for (int d = 0; d < 9; ++d)
      out[(size_t)(b0 + t) * 9 + d] = e[d] * is;
  }
}

extern "C" void kernel_launch(void* const* d_in, const int* in_sizes, int n_in,
                              void* d_out, int out_size, void* d_ws, size_t ws_size,
                              hipStream_t stream) {
  const float* feat = (const float*)d_in[0];
  // d_in[1] = category (unused by forward math)
  const float* Wt  = (const float*)d_in[2];
  const float* Wd  = (const float*)d_in[3];
  const float* mem = (const float*)d_in[4];
  float* outp = (float*)d_out;

  unsigned short* PRhi = (unsigned short*)d_ws;   // [192][768] bf16
  unsigned short* PRlo = PRhi + 192 * 768;        // [192][768] bf16

  precompute_pr<<<32, 768, 0, stream>>>(Wt, Wd, mem, PRhi, PRlo);
  const int B = in_sizes[1];   // 32768
  fused_mfma<<<B / 64, 256, 0, stream>>>(feat, PRhi, PRlo, outp);
}